// Round 1
// baseline (390.729 us; speedup 1.0000x reference)
//
#include <hip/hip_runtime.h>
#include <stdint.h>

#define NSEG 50
#define HID 128
#define KDIM 2144      // 64 + 2016 + 64
#define NROW 20000     // 400 * 50
#define NROW_PAD 20096 // 157 * 128
#define GATES 512

typedef __attribute__((ext_vector_type(8))) _Float16 f16x8;
typedef __attribute__((ext_vector_type(4))) float f32x4;

#define GLB_SPACE __attribute__((address_space(1)))
#define LDS_SPACE __attribute__((address_space(3)))

__device__ __forceinline__ void g2lds16(const void* g, void* l) {
    __builtin_amdgcn_global_load_lds((const GLB_SPACE uint32_t*)g,
                                     (LDS_SPACE uint32_t*)l, 16, 0, 0);
}

// ---------------- prep: split W_ih into fp16 hi/lo planes, cast W_hh, sum biases ---------
__global__ __launch_bounds__(256) void prep_kernel(const float* __restrict__ Wih,
                                                   const float* __restrict__ Whh,
                                                   const float* __restrict__ bih,
                                                   const float* __restrict__ bhh,
                                                   _Float16* __restrict__ wh,
                                                   _Float16* __restrict__ wl,
                                                   _Float16* __restrict__ whh16,
                                                   float* __restrict__ bias) {
    int idx = blockIdx.x * 256 + threadIdx.x;
    const int nwih = 512 * KDIM;
    const int nwhh = 512 * HID;
    if (idx < nwih) {
        float w = Wih[idx];
        _Float16 h = (_Float16)w;
        wh[idx] = h;
        // scale residual by 2^12 so it stays in fp16 normal range
        wl[idx] = (_Float16)((w - (float)h) * 4096.0f);
    } else if (idx < nwih + nwhh) {
        int q = idx - nwih;
        whh16[q] = (_Float16)Whh[q];
    } else if (idx < nwih + nwhh + 512) {
        int g = idx - nwih - nwhh;
        bias[g] = bih[g] + bhh[g];
    }
}

// ---------------- features: one block per (b, s); rank-2 levy area ----------------------
// dev_0 == 0, so S2 = (p1-p0)x(p2-p1) + (p2-p0)x(p3-p2)
__global__ __launch_bounds__(256) void feat_kernel(const float* __restrict__ x,
                                                   _Float16* __restrict__ feat) {
    int bid = blockIdx.x;          // 0..799
    int b = bid / NSEG;
    int s = bid - b * NSEG;
    int tid = threadIdx.x;

    __shared__ float pbuf[64 * 100];        // p[c][t*25+v], t in 0..3, v in 0..24
    __shared__ float2 uu[25 * 64];          // (u1,u2) per (v,c)
    __shared__ float2 vvb[25 * 64];         // (v1,v2) per (v,c)

    // load: x[b][c][4s+t][v] -> 100 contiguous floats per c
    for (int i = tid; i < 6400; i += 256) {
        int c = i / 100;
        int r = i - c * 100;
        pbuf[c * 100 + r] = x[(((size_t)b * 64 + c) * 200 + 4 * s) * 25 + r];
    }
    __syncthreads();

    // derived vectors + lvl1/start features
    for (int i = tid; i < 1600; i += 256) {
        int v = i >> 6;
        int c = i & 63;
        float p0 = pbuf[c * 100 + v];
        float p1 = pbuf[c * 100 + 25 + v];
        float p2 = pbuf[c * 100 + 50 + v];
        float p3 = pbuf[c * 100 + 75 + v];
        uu[v * 64 + c] = make_float2(p1 - p0, p2 - p0);
        vvb[v * 64 + c] = make_float2(p2 - p1, p3 - p2);
        size_t m = ((size_t)(b * 25 + v)) * NSEG + s;
        feat[m * KDIM + c] = (_Float16)(p3 - p0);            // lvl1
        feat[m * KDIM + 2080 + c] = (_Float16)p0;            // start
    }
    __syncthreads();

    // levy: 2016 upper-triangle pairs, threads over k, v inner (coalesced 2B stores)
    for (int ch = 0; ch < 8; ch++) {
        int pidx = ch * 256 + tid;
        if (pidx < 2016) {
            float disc = 16129.0f - 8.0f * (float)pidx;      // (127-2i)^2 at row starts
            int i = (int)((127.0f - sqrtf(disc)) * 0.5f);
            int off = 63 * i - (i * (i - 1)) / 2;
            while (off > pidx) { i--; off = 63 * i - (i * (i - 1)) / 2; }
            while (63 * (i + 1) - ((i + 1) * i) / 2 <= pidx) { i++; off = 63 * i - (i * (i - 1)) / 2; }
            int j = pidx - off + i + 1;
            int k = 64 + pidx;
            for (int v = 0; v < 25; v++) {
                float2 ui = uu[v * 64 + i], uj = uu[v * 64 + j];
                float2 vi = vvb[v * 64 + i], vj = vvb[v * 64 + j];
                float val = 0.5f * (ui.x * vj.x - uj.x * vi.x + ui.y * vj.y - uj.y * vi.y);
                size_t m = ((size_t)(b * 25 + v)) * NSEG + s;
                feat[m * KDIM + k] = (_Float16)val;
            }
        }
    }
}

// ---------------- GEMM: xproj = feat @ W_ih^T + bias, fp16 MFMA, W split hi/lo ----------
// BM=128, BN=128, BK=32; 4 waves, each 64x64 (4x4 tiles of 16x16x32)
__global__ __launch_bounds__(256, 2) void gemm_kernel(const _Float16* __restrict__ feat,
                                                      const _Float16* __restrict__ wh,
                                                      const _Float16* __restrict__ wl,
                                                      const float* __restrict__ bias,
                                                      float* __restrict__ xproj) {
    int bid = blockIdx.x;
    int mt = bid >> 2;
    int nb = bid & 3;
    int m0 = mt * 128;
    int n0 = nb * 128;
    int tid = threadIdx.x;
    int wave = tid >> 6;
    int lane = tid & 63;
    int quad = lane >> 4;
    int l15 = lane & 15;

    __shared__ __align__(16) _Float16 smem[3 * 128 * 32];   // A | Bh | Bl (24.5 KB)
    _Float16* As = smem;
    _Float16* Bh = smem + 128 * 32;
    _Float16* Bl = smem + 2 * 128 * 32;

    const f32x4 z4 = {0.f, 0.f, 0.f, 0.f};
    f32x4 acc1[4][4], acc2[4][4];
    for (int i = 0; i < 4; i++)
        for (int j = 0; j < 4; j++) { acc1[i][j] = z4; acc2[i][j] = z4; }

    int wm = (wave & 1) * 64;
    int wn = (wave >> 1) * 64;

    int srow = lane >> 2;            // 0..15 rows per staging instr
    int sbyte = (lane & 3) * 16;     // byte within 64B row

    const char* featB = (const char*)feat;
    const char* whB = (const char*)wh;
    const char* wlB = (const char*)wl;

    for (int kt = 0; kt < 67; kt++) {
        size_t kb = (size_t)kt * 64;   // byte offset of k0 within a row
        __syncthreads();
        {
            int R0 = wave * 32, R1 = wave * 32 + 16;
            g2lds16(featB + (size_t)(m0 + R0 + srow) * (KDIM * 2) + kb + sbyte, (char*)As + R0 * 64);
            g2lds16(featB + (size_t)(m0 + R1 + srow) * (KDIM * 2) + kb + sbyte, (char*)As + R1 * 64);
            g2lds16(whB + (size_t)(n0 + R0 + srow) * (KDIM * 2) + kb + sbyte, (char*)Bh + R0 * 64);
            g2lds16(whB + (size_t)(n0 + R1 + srow) * (KDIM * 2) + kb + sbyte, (char*)Bh + R1 * 64);
            g2lds16(wlB + (size_t)(n0 + R0 + srow) * (KDIM * 2) + kb + sbyte, (char*)Bl + R0 * 64);
            g2lds16(wlB + (size_t)(n0 + R1 + srow) * (KDIM * 2) + kb + sbyte, (char*)Bl + R1 * 64);
        }
        __syncthreads();

        f16x8 afrag[4];
        for (int mtl = 0; mtl < 4; mtl++)
            afrag[mtl] = *(const f16x8*)((const char*)As + (wm + mtl * 16 + l15) * 64 + quad * 16);
        for (int ntl = 0; ntl < 4; ntl++) {
            f16x8 bhf = *(const f16x8*)((const char*)Bh + (wn + ntl * 16 + l15) * 64 + quad * 16);
            f16x8 blf = *(const f16x8*)((const char*)Bl + (wn + ntl * 16 + l15) * 64 + quad * 16);
            for (int mtl = 0; mtl < 4; mtl++) {
                acc1[mtl][ntl] = __builtin_amdgcn_mfma_f32_16x16x32_f16(afrag[mtl], bhf, acc1[mtl][ntl], 0, 0, 0);
                acc2[mtl][ntl] = __builtin_amdgcn_mfma_f32_16x16x32_f16(afrag[mtl], blf, acc2[mtl][ntl], 0, 0, 0);
            }
        }
    }

    for (int ntl = 0; ntl < 4; ntl++) {
        int n = n0 + wn + ntl * 16 + l15;
        float bv = bias[n];
        for (int mtl = 0; mtl < 4; mtl++) {
            for (int r = 0; r < 4; r++) {
                int m = m0 + wm + mtl * 16 + quad * 4 + r;
                if (m < NROW)
                    xproj[(size_t)m * GATES + n] =
                        acc1[mtl][ntl][r] + acc2[mtl][ntl][r] * (1.0f / 4096.0f) + bv;
            }
        }
    }
}

// ---------------- LSTM: block = 16 sequences, 8 waves; wave w owns hid chunk w*16 -------
__global__ __launch_bounds__(512, 2) void lstm_kernel(const float* __restrict__ xproj,
                                                      const _Float16* __restrict__ whh,
                                                      float* __restrict__ out) {
    int bid = blockIdx.x;        // 0..24
    int n0 = bid * 16;
    int tid = threadIdx.x;
    int wave = tid >> 6;
    int lane = tid & 63;
    int quad = lane >> 4;
    int col = lane & 15;
    int H0 = wave * 16;

    __shared__ __align__(16) _Float16 hbuf[16 * 136];   // [seq][hid], padded 128->136
    __shared__ float h32[128 * 16];                     // [hid][seq]

    // W_hh fragments held in VGPRs for all 50 steps. B[k][n] = whh[n][k].
    f16x8 bfrag[4][4];
    for (int gi = 0; gi < 4; gi++) {
        int n = gi * 128 + H0 + col;
        for (int q = 0; q < 4; q++)
            bfrag[gi][q] = *(const f16x8*)(whh + (size_t)n * HID + q * 32 + quad * 8);
    }
    for (int i = tid; i < 16 * 136; i += 512) hbuf[i] = (_Float16)0.0f;
    float c[4] = {0.f, 0.f, 0.f, 0.f};
    __syncthreads();

    const f32x4 z4 = {0.f, 0.f, 0.f, 0.f};
    for (int s = 0; s < NSEG; s++) {
        // prefetch x_proj (bias already folded in)
        float xp[4][4];
        for (int gi = 0; gi < 4; gi++) {
            int g = gi * 128 + H0 + col;
            for (int r = 0; r < 4; r++) {
                int seq = quad * 4 + r;
                xp[gi][r] = xproj[((size_t)(n0 + seq) * NSEG + s) * GATES + g];
            }
        }
        // A-frags: A[m=col][k] from h_{s-1}
        f16x8 afrag[4];
        for (int q = 0; q < 4; q++)
            afrag[q] = *(const f16x8*)(&hbuf[col * 136 + q * 32 + quad * 8]);

        f32x4 acc[4];
        for (int gi = 0; gi < 4; gi++) {
            acc[gi] = z4;
            for (int q = 0; q < 4; q++)
                acc[gi] = __builtin_amdgcn_mfma_f32_16x16x32_f16(afrag[q], bfrag[gi][q], acc[gi], 0, 0, 0);
        }
        __syncthreads();   // all reads of hbuf done

        float hv[4];
        for (int r = 0; r < 4; r++) {
            float ip = acc[0][r] + xp[0][r];
            float fp = acc[1][r] + xp[1][r];
            float gp = acc[2][r] + xp[2][r];
            float op = acc[3][r] + xp[3][r];
            float si = __fdividef(1.0f, 1.0f + __expf(-ip));
            float sf = __fdividef(1.0f, 1.0f + __expf(-fp));
            float so = __fdividef(1.0f, 1.0f + __expf(-op));
            float eg = __expf(-2.0f * gp);
            float tg = __fdividef(1.0f - eg, 1.0f + eg);
            c[r] = sf * c[r] + si * tg;
            float ec = __expf(-2.0f * c[r]);
            float tc = __fdividef(1.0f - ec, 1.0f + ec);
            hv[r] = so * tc;
        }
        for (int r = 0; r < 4; r++) {
            int seq = quad * 4 + r;
            hbuf[seq * 136 + H0 + col] = (_Float16)hv[r];
            h32[(H0 + col) * 16 + seq] = hv[r];
        }
        __syncthreads();   // writes visible

        // out[b][hid][s][v], staged via h32 so stores are v-contiguous runs
        for (int it = 0; it < 4; it++) {
            int flat = it * 512 + tid;
            int hid = flat >> 4;
            int seq = flat & 15;
            int n = n0 + seq;
            int bb = n / 25;
            int v = n - bb * 25;
            out[(((size_t)bb * 128 + hid) * NSEG + s) * 25 + v] = h32[hid * 16 + seq];
        }
    }
}

extern "C" void kernel_launch(void* const* d_in, const int* in_sizes, int n_in,
                              void* d_out, int out_size, void* d_ws, size_t ws_size,
                              hipStream_t stream) {
    const float* x = (const float*)d_in[0];
    const float* Wih = (const float*)d_in[1];
    const float* Whh = (const float*)d_in[2];
    const float* bih = (const float*)d_in[3];
    const float* bhh = (const float*)d_in[4];
    float* out = (float*)d_out;

    char* ws = (char*)d_ws;
    size_t off = 0;
    _Float16* feat = (_Float16*)(ws + off); off += (size_t)NROW_PAD * KDIM * 2;   // 86.2 MB
    float* xproj = (float*)(ws + off);      off += (size_t)NROW_PAD * GATES * 4;  // 41.2 MB
    _Float16* wh = (_Float16*)(ws + off);   off += (size_t)512 * KDIM * 2;
    _Float16* wl = (_Float16*)(ws + off);   off += (size_t)512 * KDIM * 2;
    _Float16* whh16 = (_Float16*)(ws + off); off += (size_t)512 * HID * 2;
    float* bias = (float*)(ws + off);       off += 512 * 4;

    int prep_total = 512 * KDIM + 512 * HID + 512;
    hipLaunchKernelGGL(prep_kernel, dim3((prep_total + 255) / 256), dim3(256), 0, stream,
                       Wih, Whh, bih, bhh, wh, wl, whh16, bias);
    hipLaunchKernelGGL(feat_kernel, dim3(16 * NSEG), dim3(256), 0, stream, x, feat);
    hipLaunchKernelGGL(gemm_kernel, dim3(157 * 4), dim3(256), 0, stream, feat, wh, wl, bias, xproj);
    hipLaunchKernelGGL(lstm_kernel, dim3(25), dim3(512), 0, stream, xproj, whh16, out);
}

// Round 2
// 340.778 us; speedup vs baseline: 1.1466x; 1.1466x over previous
//
#include <hip/hip_runtime.h>
#include <stdint.h>

#define NSEG 50
#define HID 128
#define KDIM 2144      // 64 + 2016 + 64
#define NROW 20000     // 400 * 50
#define NROW_PAD 20096 // 157 * 128
#define GATES 512

typedef __attribute__((ext_vector_type(8))) _Float16 f16x8;
typedef __attribute__((ext_vector_type(4))) float f32x4;

#define GLB_SPACE __attribute__((address_space(1)))
#define LDS_SPACE __attribute__((address_space(3)))

__device__ __forceinline__ void g2lds16(const void* g, void* l) {
    __builtin_amdgcn_global_load_lds((const GLB_SPACE uint32_t*)g,
                                     (LDS_SPACE uint32_t*)l, 16, 0, 0);
}

// ---------------- prep: cast W_ih and W_hh to fp16, sum biases ---------------------------
__global__ __launch_bounds__(256) void prep_kernel(const float* __restrict__ Wih,
                                                   const float* __restrict__ Whh,
                                                   const float* __restrict__ bih,
                                                   const float* __restrict__ bhh,
                                                   _Float16* __restrict__ wh,
                                                   _Float16* __restrict__ whh16,
                                                   float* __restrict__ bias) {
    int idx = blockIdx.x * 256 + threadIdx.x;
    const int nwih = 512 * KDIM;
    const int nwhh = 512 * HID;
    if (idx < nwih) {
        wh[idx] = (_Float16)Wih[idx];
    } else if (idx < nwih + nwhh) {
        int q = idx - nwih;
        whh16[q] = (_Float16)Whh[q];
    } else if (idx < nwih + nwhh + 512) {
        int g = idx - nwih - nwhh;
        bias[g] = bih[g] + bhh[g];
    }
}

// ---------------- features: one block per (b, s); rank-2 levy area ----------------------
// dev_0 == 0, so S2 = (p1-p0)x(p2-p1) + (p2-p0)x(p3-p2)
__global__ __launch_bounds__(256) void feat_kernel(const float* __restrict__ x,
                                                   _Float16* __restrict__ feat) {
    int bid = blockIdx.x;          // 0..799
    int b = bid / NSEG;
    int s = bid - b * NSEG;
    int tid = threadIdx.x;

    __shared__ float pbuf[64 * 100];        // p[c][t*25+v], t in 0..3, v in 0..24
    __shared__ float2 uu[25 * 64];          // (u1,u2) per (v,c)
    __shared__ float2 vvb[25 * 64];         // (v1,v2) per (v,c)

    // load: x[b][c][4s+t][v] -> 100 contiguous floats per c
    for (int i = tid; i < 6400; i += 256) {
        int c = i / 100;
        int r = i - c * 100;
        pbuf[c * 100 + r] = x[(((size_t)b * 64 + c) * 200 + 4 * s) * 25 + r];
    }
    __syncthreads();

    // derived vectors + lvl1/start features
    for (int i = tid; i < 1600; i += 256) {
        int v = i >> 6;
        int c = i & 63;
        float p0 = pbuf[c * 100 + v];
        float p1 = pbuf[c * 100 + 25 + v];
        float p2 = pbuf[c * 100 + 50 + v];
        float p3 = pbuf[c * 100 + 75 + v];
        uu[v * 64 + c] = make_float2(p1 - p0, p2 - p0);
        vvb[v * 64 + c] = make_float2(p2 - p1, p3 - p2);
        size_t m = ((size_t)(b * 25 + v)) * NSEG + s;
        feat[m * KDIM + c] = (_Float16)(p3 - p0);            // lvl1
        feat[m * KDIM + 2080 + c] = (_Float16)p0;            // start
    }
    __syncthreads();

    // levy: 2016 upper-triangle pairs, threads over k, v inner
    for (int ch = 0; ch < 8; ch++) {
        int pidx = ch * 256 + tid;
        if (pidx < 2016) {
            float disc = 16129.0f - 8.0f * (float)pidx;      // (127-2i)^2 at row starts
            int i = (int)((127.0f - sqrtf(disc)) * 0.5f);
            int off = 63 * i - (i * (i - 1)) / 2;
            while (off > pidx) { i--; off = 63 * i - (i * (i - 1)) / 2; }
            while (63 * (i + 1) - ((i + 1) * i) / 2 <= pidx) { i++; off = 63 * i - (i * (i - 1)) / 2; }
            int j = pidx - off + i + 1;
            int k = 64 + pidx;
            for (int v = 0; v < 25; v++) {
                float2 ui = uu[v * 64 + i], uj = uu[v * 64 + j];
                float2 vi = vvb[v * 64 + i], vj = vvb[v * 64 + j];
                float val = 0.5f * (ui.x * vj.x - uj.x * vi.x + ui.y * vj.y - uj.y * vi.y);
                size_t m = ((size_t)(b * 25 + v)) * NSEG + s;
                feat[m * KDIM + k] = (_Float16)val;
            }
        }
    }
}

// ---------------- GEMM: xproj = feat @ W_ih^T + bias, single-plane fp16 MFMA ------------
// BM=128, BN=64, BK=32; 1256 blocks (fully resident), 4 waves, wave tile 64x32.
// nb = bid/157 keeps same-nb blocks contiguous: B chunk (274 KB) L2-resident per XCD,
// feat rows fetched from HBM once (LLC serves the 8 nb-siblings).
__global__ __launch_bounds__(256, 4) void gemm_kernel(const _Float16* __restrict__ feat,
                                                      const _Float16* __restrict__ wh,
                                                      const float* __restrict__ bias,
                                                      float* __restrict__ xproj) {
    int bid = blockIdx.x;
    int nb = bid / 157;            // 0..7
    int mt = bid - nb * 157;       // 0..156
    int m0 = mt * 128;
    int n0 = nb * 64;
    int tid = threadIdx.x;
    int wave = tid >> 6;
    int lane = tid & 63;
    int quad = lane >> 4;
    int l15 = lane & 15;

    __shared__ __align__(16) _Float16 smem[(128 + 64) * 32];   // A | B (12 KB)
    _Float16* As = smem;
    _Float16* Bs = smem + 128 * 32;

    const f32x4 z4 = {0.f, 0.f, 0.f, 0.f};
    f32x4 acc[4][2];
    for (int i = 0; i < 4; i++)
        for (int j = 0; j < 2; j++) acc[i][j] = z4;

    int wm = (wave & 1) * 64;      // 0 or 64
    int wn = (wave >> 1) * 32;     // 0 or 32

    int srow = lane >> 2;          // 0..15 rows per staging instr
    int sbyte = (lane & 3) * 16;   // byte within 64B row

    const char* featB = (const char*)feat;
    const char* whB = (const char*)wh;

    for (int kt = 0; kt < 67; kt++) {
        size_t kb = (size_t)kt * 64;   // byte offset of k0 within a row
        __syncthreads();
        {
            int R0 = wave * 32, R1 = wave * 32 + 16;
            g2lds16(featB + (size_t)(m0 + R0 + srow) * (KDIM * 2) + kb + sbyte, (char*)As + R0 * 64);
            g2lds16(featB + (size_t)(m0 + R1 + srow) * (KDIM * 2) + kb + sbyte, (char*)As + R1 * 64);
            g2lds16(whB + (size_t)(n0 + wave * 16 + srow) * (KDIM * 2) + kb + sbyte, (char*)Bs + wave * 16 * 64);
        }
        __syncthreads();

        f16x8 bfrag[2];
        for (int ntl = 0; ntl < 2; ntl++)
            bfrag[ntl] = *(const f16x8*)((const char*)Bs + (wn + ntl * 16 + l15) * 64 + quad * 16);
        for (int mtl = 0; mtl < 4; mtl++) {
            f16x8 afrag = *(const f16x8*)((const char*)As + (wm + mtl * 16 + l15) * 64 + quad * 16);
            for (int ntl = 0; ntl < 2; ntl++)
                acc[mtl][ntl] = __builtin_amdgcn_mfma_f32_16x16x32_f16(afrag, bfrag[ntl], acc[mtl][ntl], 0, 0, 0);
        }
    }

    for (int ntl = 0; ntl < 2; ntl++) {
        int n = n0 + wn + ntl * 16 + l15;
        float bv = bias[n];
        for (int mtl = 0; mtl < 4; mtl++) {
            for (int r = 0; r < 4; r++) {
                int m = m0 + wm + mtl * 16 + quad * 4 + r;
                if (m < NROW)
                    xproj[(size_t)m * GATES + n] = acc[mtl][ntl][r] + bv;
            }
        }
    }
}

// ---------------- LSTM: block = 16 sequences, 8 waves; wave w owns hid chunk w*16 -------
__global__ __launch_bounds__(512, 2) void lstm_kernel(const float* __restrict__ xproj,
                                                      const _Float16* __restrict__ whh,
                                                      float* __restrict__ out) {
    int bid = blockIdx.x;        // 0..24
    int n0 = bid * 16;
    int tid = threadIdx.x;
    int wave = tid >> 6;
    int lane = tid & 63;
    int quad = lane >> 4;
    int col = lane & 15;
    int H0 = wave * 16;

    __shared__ __align__(16) _Float16 hbuf[16 * 136];   // [seq][hid], padded 128->136
    __shared__ float h32[128 * 16];                     // [hid][seq]

    // W_hh fragments held in VGPRs for all 50 steps. B[k][n] = whh[n][k].
    f16x8 bfrag[4][4];
    for (int gi = 0; gi < 4; gi++) {
        int n = gi * 128 + H0 + col;
        for (int q = 0; q < 4; q++)
            bfrag[gi][q] = *(const f16x8*)(whh + (size_t)n * HID + q * 32 + quad * 8);
    }
    for (int i = tid; i < 16 * 136; i += 512) hbuf[i] = (_Float16)0.0f;
    float c[4] = {0.f, 0.f, 0.f, 0.f};
    __syncthreads();

    // software-pipelined x_proj: xp holds step s, xpn prefetches s+1
    float xp[4][4];
    for (int gi = 0; gi < 4; gi++) {
        int g = gi * 128 + H0 + col;
        for (int r = 0; r < 4; r++) {
            int seq = quad * 4 + r;
            xp[gi][r] = xproj[((size_t)(n0 + seq) * NSEG + 0) * GATES + g];
        }
    }

    const f32x4 z4 = {0.f, 0.f, 0.f, 0.f};
    for (int s = 0; s < NSEG; s++) {
        // A-frags: A[m=col][k] from h_{s-1}
        f16x8 afrag[4];
        for (int q = 0; q < 4; q++)
            afrag[q] = *(const f16x8*)(&hbuf[col * 136 + q * 32 + quad * 8]);

        f32x4 acc[4];
        for (int gi = 0; gi < 4; gi++) {
            acc[gi] = z4;
            for (int q = 0; q < 4; q++)
                acc[gi] = __builtin_amdgcn_mfma_f32_16x16x32_f16(afrag[q], bfrag[gi][q], acc[gi], 0, 0, 0);
        }

        // prefetch next step's x_proj while MFMA + barriers are in flight
        float xpn[4][4];
        if (s + 1 < NSEG) {
            for (int gi = 0; gi < 4; gi++) {
                int g = gi * 128 + H0 + col;
                for (int r = 0; r < 4; r++) {
                    int seq = quad * 4 + r;
                    xpn[gi][r] = xproj[((size_t)(n0 + seq) * NSEG + (s + 1)) * GATES + g];
                }
            }
        }
        __syncthreads();   // all reads of hbuf done

        float hv[4];
        for (int r = 0; r < 4; r++) {
            float ip = acc[0][r] + xp[0][r];
            float fp = acc[1][r] + xp[1][r];
            float gp = acc[2][r] + xp[2][r];
            float op = acc[3][r] + xp[3][r];
            float si = __fdividef(1.0f, 1.0f + __expf(-ip));
            float sf = __fdividef(1.0f, 1.0f + __expf(-fp));
            float so = __fdividef(1.0f, 1.0f + __expf(-op));
            float eg = __expf(-2.0f * gp);
            float tg = __fdividef(1.0f - eg, 1.0f + eg);
            c[r] = sf * c[r] + si * tg;
            float ec = __expf(-2.0f * c[r]);
            float tc = __fdividef(1.0f - ec, 1.0f + ec);
            hv[r] = so * tc;
        }
        for (int r = 0; r < 4; r++) {
            int seq = quad * 4 + r;
            hbuf[seq * 136 + H0 + col] = (_Float16)hv[r];
            h32[(H0 + col) * 16 + seq] = hv[r];
        }
        __syncthreads();   // writes visible

        // out[b][hid][s][v], staged via h32 so stores are v-contiguous runs
        for (int it = 0; it < 4; it++) {
            int flat = it * 512 + tid;
            int hid = flat >> 4;
            int seq = flat & 15;
            int n = n0 + seq;
            int bb = n / 25;
            int v = n - bb * 25;
            out[(((size_t)bb * 128 + hid) * NSEG + s) * 25 + v] = h32[hid * 16 + seq];
        }

        for (int gi = 0; gi < 4; gi++)
            for (int r = 0; r < 4; r++)
                xp[gi][r] = xpn[gi][r];
    }
}

extern "C" void kernel_launch(void* const* d_in, const int* in_sizes, int n_in,
                              void* d_out, int out_size, void* d_ws, size_t ws_size,
                              hipStream_t stream) {
    const float* x = (const float*)d_in[0];
    const float* Wih = (const float*)d_in[1];
    const float* Whh = (const float*)d_in[2];
    const float* bih = (const float*)d_in[3];
    const float* bhh = (const float*)d_in[4];
    float* out = (float*)d_out;

    char* ws = (char*)d_ws;
    size_t off = 0;
    _Float16* feat = (_Float16*)(ws + off); off += (size_t)NROW_PAD * KDIM * 2;   // 86.2 MB
    float* xproj = (float*)(ws + off);      off += (size_t)NROW_PAD * GATES * 4;  // 41.2 MB
    _Float16* wh = (_Float16*)(ws + off);   off += (size_t)512 * KDIM * 2;
    _Float16* whh16 = (_Float16*)(ws + off); off += (size_t)512 * HID * 2;
    float* bias = (float*)(ws + off);       off += 512 * 4;

    int prep_total = 512 * KDIM + 512 * HID + 512;
    hipLaunchKernelGGL(prep_kernel, dim3((prep_total + 255) / 256), dim3(256), 0, stream,
                       Wih, Whh, bih, bhh, wh, whh16, bias);
    hipLaunchKernelGGL(feat_kernel, dim3(16 * NSEG), dim3(256), 0, stream, x, feat);
    hipLaunchKernelGGL(gemm_kernel, dim3(157 * 8), dim3(256), 0, stream, feat, wh, bias, xproj);
    hipLaunchKernelGGL(lstm_kernel, dim3(25), dim3(512), 0, stream, xproj, whh16, out);
}